// Round 11
// baseline (1525.766 us; speedup 1.0000x reference)
//
#include <hip/hip_runtime.h>

#define NN 50000
#define EE 800000

// canonical bf16 region: element offsets (original layouts)
#define C_X    0
#define C_FCW  6400000
#define C_AL   6416384
#define C_AR   6416512
#define C_LNG  6416640
#define C_LNB  6416768
#define C_W1   6416896
#define C_B1   6482432
#define C_W2   6482944
#define C_B2   6548480
#define C_TOT  6548608

__device__ __forceinline__ float bf2f(unsigned short u) {
  union { unsigned int i; float f; } v; v.i = ((unsigned int)u) << 16; return v.f;
}
__device__ __forceinline__ unsigned short f2bf(float f) {
  union { float f; unsigned int i; } v; v.f = f;
  unsigned int r = v.i + 0x7fffu + ((v.i >> 16) & 1u);
  return (unsigned short)(r >> 16);
}
__device__ __forceinline__ int ld_idx(const void* p, int i, int is64) {
  return is64 ? (int)((const long long*)p)[i] : ((const int*)p)[i];
}

// ---- float dtype probe on x (fires for fp32: low halves hit 0x7F80 exp ~1/256) ----
__global__ void k_detect(const unsigned short* __restrict__ xr, int* __restrict__ flag) {
  int i = blockIdx.x * 256 + threadIdx.x;
  int bad = 0, zc = 0;
  for (int j = i; j < 65536; j += 32 * 256) {
    unsigned short u = xr[j];
    if ((u & 0x7F80u) == 0x7F80u) bad = 1;
    if (((j & 1) == 0) && u == 0) zc++;
  }
  if (bad) atomicOr(&flag[0], 1);
  if (zc) atomicAdd(&flag[1], zc);
}

// ---- int width probe for src/dst ----
__global__ void k_detect_int(const int* __restrict__ s, const int* __restrict__ d,
                             int* __restrict__ iflags) {
  int i = blockIdx.x * 256 + threadIdx.x;
  int zs = 0, zd = 0;
  for (int j = i; j < 131072; j += 32 * 256) {
    if (j & 1) {
      if (s[j] == 0) zs++;
      if (d[j] == 0) zd++;
    }
  }
  if (zs) atomicAdd(&iflags[0], zs);
  if (zd) atomicAdd(&iflags[1], zd);
}

// ---- canonicalize float inputs -> bf16 canon (fp32 converted, bf16 passthrough) ----
__global__ __launch_bounds__(256) void k_convert(
    const void* __restrict__ x, const void* __restrict__ fcw,
    const void* __restrict__ a_l, const void* __restrict__ a_r,
    const void* __restrict__ lng, const void* __restrict__ lnb,
    const void* __restrict__ w1, const void* __restrict__ b1,
    const void* __restrict__ w2, const void* __restrict__ b2,
    const int* __restrict__ flag, unsigned short* __restrict__ canon) {
  const int isf32 = (flag[0] != 0) || (flag[1] > 8192);
  for (int i = blockIdx.x * 256 + threadIdx.x; i < C_TOT; i += gridDim.x * 256) {
    const void* src; int idx;
    if (i < C_FCW)      { src = x;   idx = i; }
    else if (i < C_AL)  { src = fcw; idx = i - C_FCW; }
    else if (i < C_AR)  { src = a_l; idx = i - C_AL; }
    else if (i < C_LNG) { src = a_r; idx = i - C_AR; }
    else if (i < C_LNB) { src = lng; idx = i - C_LNG; }
    else if (i < C_W1)  { src = lnb; idx = i - C_LNB; }
    else if (i < C_B1)  { src = w1;  idx = i - C_W1; }
    else if (i < C_W2)  { src = b1;  idx = i - C_B1; }
    else if (i < C_B2)  { src = w2;  idx = i - C_W2; }
    else                { src = b2;  idx = i - C_B2; }
    unsigned short v;
    if (isf32) v = f2bf(((const float*)src)[idx]);
    else       v = ((const unsigned short*)src)[idx];
    canon[i] = v;
  }
}

// ---- projection: z[n][c] = sum_d x[n][d] * fc_w[c/16][d][c%16] (z bf16) ----
__global__ __launch_bounds__(256) void k_project_s(
    const unsigned short* __restrict__ canon, unsigned short* __restrict__ z) {
  int idx = blockIdx.x * 256 + threadIdx.x;
  if (idx >= NN * 128) return;
  const unsigned short* xc = canon + C_X;
  const unsigned short* fw = canon + C_FCW;
  int n = idx >> 7, c = idx & 127;
  int h = c >> 4, o = c & 15;
  float acc = 0.f;
  for (int d = 0; d < 128; d++)
    acc += bf2f(xc[n * 128 + d]) * bf2f(fw[h * 2048 + d * 16 + o]);
  z[idx] = f2bf(acc);
}

// ---- el/er ----
__global__ __launch_bounds__(256) void k_el(
    const unsigned short* __restrict__ canon, const unsigned short* __restrict__ z,
    float* __restrict__ el, float* __restrict__ er) {
  int idx = blockIdx.x * 256 + threadIdx.x;
  if (idx >= NN * 8) return;
  const unsigned short* alc = canon + C_AL;
  const unsigned short* arc = canon + C_AR;
  int n = idx >> 3, h = idx & 7;
  float sl = 0.f, sr = 0.f;
  for (int o = 0; o < 16; o++) {
    float zv = bf2f(z[n * 128 + h * 16 + o]);
    sl += zv * bf2f(alc[h * 16 + o]);
    sr += zv * bf2f(arc[h * 16 + o]);
  }
  el[idx] = sl; er[idx] = sr;
}

// ---------------- CSR build (width-aware; integrity verified in R8) ----------------
__global__ void k_hist(const void* __restrict__ dst, const int* __restrict__ iflags,
                       int* __restrict__ cnt) {
  int i = blockIdx.x * 256 + threadIdx.x;
  if (i < EE) {
    int d64 = iflags[1] > 1000;
    unsigned d = (unsigned)ld_idx(dst, i, d64); if (d >= NN) d = 0;
    atomicAdd(&cnt[d], 1);
  }
}

__global__ __launch_bounds__(1024) void k_scan(const int* __restrict__ cnt,
                                               int* __restrict__ offs, int* __restrict__ cursor) {
  __shared__ int wtot[16];
  const int tid = threadIdx.x;
  const int lane = tid & 63, wid = tid >> 6;
  int carry = 0;
  for (int base = 0; base < NN; base += 4096) {
    int i0 = base + tid * 4;
    int c0 = 0, c1 = 0, c2 = 0, c3 = 0;
    if (i0 + 3 < NN) { int4 v = *(const int4*)(cnt + i0); c0 = v.x; c1 = v.y; c2 = v.z; c3 = v.w; }
    else {
      if (i0 < NN) c0 = cnt[i0];
      if (i0 + 1 < NN) c1 = cnt[i0 + 1];
      if (i0 + 2 < NN) c2 = cnt[i0 + 2];
      if (i0 + 3 < NN) c3 = cnt[i0 + 3];
    }
    int s = c0 + c1 + c2 + c3;
    int incl = s;
#pragma unroll
    for (int off = 1; off < 64; off <<= 1) {
      int t = __shfl_up(incl, off);
      if (lane >= off) incl += t;
    }
    if (lane == 63) wtot[wid] = incl;
    __syncthreads();
    int wbase = 0, total = 0;
    for (int j = 0; j < 16; j++) { int t = wtot[j]; total += t; if (j < wid) wbase += t; }
    int excl = carry + wbase + incl - s;
    if (i0 < NN) { offs[i0] = excl; cursor[i0] = excl; }
    if (i0 + 1 < NN) { offs[i0 + 1] = excl + c0; cursor[i0 + 1] = excl + c0; }
    if (i0 + 2 < NN) { offs[i0 + 2] = excl + c0 + c1; cursor[i0 + 2] = excl + c0 + c1; }
    if (i0 + 3 < NN) { offs[i0 + 3] = excl + c0 + c1 + c2; cursor[i0 + 3] = excl + c0 + c1 + c2; }
    carry += total;
    __syncthreads();
  }
  if (tid == 0) offs[NN] = carry;
}

__global__ void k_fill(const void* __restrict__ src, const void* __restrict__ dst,
                       const int* __restrict__ iflags,
                       int* __restrict__ cursor, int* __restrict__ esrc) {
  int i = blockIdx.x * 256 + threadIdx.x;
  if (i < EE) {
    int s64 = iflags[0] > 1000, d64 = iflags[1] > 1000;
    unsigned d = (unsigned)ld_idx(dst, i, d64); if (d >= NN) d = 0;
    int p = atomicAdd(&cursor[d], 1);
    unsigned s = (unsigned)ld_idx(src, i, s64); if (s >= NN) s = 0;
    if ((unsigned)p < EE) esrc[p] = (int)s;
  }
}

// ---- per-(node,head) softmax stats ----
__global__ __launch_bounds__(256) void k_soft(
    const float* __restrict__ el, const float* __restrict__ er,
    const int* __restrict__ offs, const int* __restrict__ esrc,
    float* __restrict__ marr, float* __restrict__ darr) {
  int idx = blockIdx.x * 256 + threadIdx.x;
  if (idx >= NN * 8) return;
  int n = idx >> 3, h = idx & 7;
  int beg = offs[n];
  int deg = offs[n + 1] - beg;
  if (deg < 0 || deg > EE) deg = 0;
  float ern = er[idx];
  float m = -3.0e38f;
  for (int i = 0; i < deg; i++) {
    unsigned s = (unsigned)esrc[beg + i]; if (s >= NN) s = 0;
    float t = el[s * 8 + h] + ern;
    t = (t > 0.f) ? t : 0.01f * t;
    m = fmaxf(m, t);
  }
  if (deg == 0) m = 0.f;
  float den = 0.f;
  for (int i = 0; i < deg; i++) {
    unsigned s = (unsigned)esrc[beg + i]; if (s >= NN) s = 0;
    float t = el[s * 8 + h] + ern;
    t = (t > 0.f) ? t : 0.01f * t;
    den += expf(fminf(t - m, 0.f));
  }
  marr[idx] = m; darr[idx] = den;
}

// ---- per-(node,col) aggregate + elu + residual -> h1 (fp32, staged in d_out) ----
__global__ __launch_bounds__(256) void k_agg_s(
    const unsigned short* __restrict__ canon, const unsigned short* __restrict__ z,
    const float* __restrict__ el, const float* __restrict__ er,
    const float* __restrict__ marr, const float* __restrict__ darr,
    const int* __restrict__ offs, const int* __restrict__ esrc,
    float* __restrict__ h1out) {
  int idx = blockIdx.x * 256 + threadIdx.x;
  if (idx >= NN * 128) return;
  const unsigned short* xc = canon + C_X;
  int n = idx >> 7, c = idx & 127, h = c >> 4;
  int beg = offs[n];
  int deg = offs[n + 1] - beg;
  if (deg < 0 || deg > EE) deg = 0;
  float ern = er[n * 8 + h];
  float m = marr[n * 8 + h];
  float den = darr[n * 8 + h];
  float acc = 0.f;
  for (int i = 0; i < deg; i++) {
    unsigned s = (unsigned)esrc[beg + i]; if (s >= NN) s = 0;
    float t = el[s * 8 + h] + ern;
    t = (t > 0.f) ? t : 0.01f * t;
    acc += expf(fminf(t - m, 0.f)) * bf2f(z[s * 128 + c]);
  }
  float r = (den > 0.f) ? acc / den : 0.f;
  float hv = ((r > 0.f) ? r : (expf(fminf(r, 0.f)) - 1.f)) + bf2f(xc[idx]);
  h1out[idx] = hv;
}

// ---- per-node FFN: LN -> inter=gelu(ln@w1+b1) -> out = inter@w2+b2+h (fp32) ----
__global__ __launch_bounds__(256) void k_ffnrow(
    const unsigned short* __restrict__ canon, float* __restrict__ out) {
  const unsigned short* lngc = canon + C_LNG;
  const unsigned short* lnbc = canon + C_LNB;
  const unsigned short* w1c  = canon + C_W1;
  const unsigned short* b1c  = canon + C_B1;
  const unsigned short* w2c  = canon + C_W2;
  const unsigned short* b2c  = canon + C_B2;
  __shared__ float shh[128];
  __shared__ float sln[128];
  __shared__ float sint[512];
  __shared__ float s_mu, s_rstd;
  const int t = threadIdx.x;
  const int node = blockIdx.x;
  if (t < 128) shh[t] = out[node * 128 + t];  // h1 staged fp32 in d_out
  __syncthreads();
  if (t == 0) {
    float s = 0.f;
    for (int i = 0; i < 128; i++) s += shh[i];
    float mu = s * (1.f / 128.f);
    float v = 0.f;
    for (int i = 0; i < 128; i++) { float d = shh[i] - mu; v += d * d; }
    s_mu = mu;
    s_rstd = rsqrtf(v * (1.f / 128.f) + 1e-6f);
  }
  __syncthreads();
  if (t < 128)
    sln[t] = (shh[t] - s_mu) * s_rstd * bf2f(lngc[t]) + bf2f(lnbc[t]);
  __syncthreads();
  for (int f = t; f < 512; f += 256) {
    float a = bf2f(b1c[f]);
    for (int k = 0; k < 128; k++) a += sln[k] * bf2f(w1c[k * 512 + f]);
    sint[f] = 0.5f * a * (1.f + erff(a * 0.7071067811865475f));
  }
  __syncthreads();
  if (t < 128) {
    float a = bf2f(b2c[t]);
    for (int f = 0; f < 512; f++) a += sint[f] * bf2f(w2c[f * 128 + t]);
    out[node * 128 + t] = a + shh[t];
  }
}

extern "C" void kernel_launch(void* const* d_in, const int* in_sizes, int n_in,
                              void* d_out, int out_size, void* d_ws, size_t ws_size,
                              hipStream_t stream) {
  const void* x   = d_in[0];
  const void* fcw = d_in[1];
  const void* a_l = d_in[2];
  const void* a_r = d_in[3];
  const void* lng = d_in[4];
  const void* lnb = d_in[5];
  const void* w1  = d_in[6];
  const void* b1  = d_in[7];
  const void* w2  = d_in[8];
  const void* b2  = d_in[9];
  const void* src = d_in[10];
  const void* dst = d_in[11];
  float* out = (float*)d_out;  // fp32 output (R8/R10 evidence)

  char* ws = (char*)d_ws;
  size_t off = 0;
  auto alloc = [&](size_t bytes) -> char* {
    char* p = ws + off; off += (bytes + 255) & ~(size_t)255; return p;
  };
  int* flags            = (int*)alloc(64);   // [0,1]=float probe, [2,3]=int widths
  int* fflags           = flags;
  int* iflags           = flags + 2;
  int* cnt              = (int*)alloc((size_t)NN * 4);
  int* offs             = (int*)alloc((size_t)(NN + 1) * 4);
  int* cursor           = (int*)alloc((size_t)NN * 4);
  int* esrc             = (int*)alloc((size_t)EE * 4);
  unsigned short* canon = (unsigned short*)alloc((size_t)C_TOT * 2);
  unsigned short* z     = (unsigned short*)alloc((size_t)NN * 128 * 2);
  float* el             = (float*)alloc((size_t)NN * 8 * 4);
  float* er             = (float*)alloc((size_t)NN * 8 * 4);
  float* marr           = (float*)alloc((size_t)NN * 8 * 4);
  float* darr           = (float*)alloc((size_t)NN * 8 * 4);
  // total ≈ 36.1 MB (< verified-safe 36.5 MB)

  hipMemsetAsync(ws, 0, 256 + (size_t)NN * 4, stream);  // flags + cnt
  k_detect<<<32, 256, 0, stream>>>((const unsigned short*)x, fflags);
  k_detect_int<<<32, 256, 0, stream>>>((const int*)src, (const int*)dst, iflags);
  k_convert<<<2048, 256, 0, stream>>>(x, fcw, a_l, a_r, lng, lnb, w1, b1, w2, b2, fflags, canon);
  k_project_s<<<(NN * 128 + 255) / 256, 256, 0, stream>>>(canon, z);
  k_el<<<(NN * 8 + 255) / 256, 256, 0, stream>>>(canon, z, el, er);
  k_hist<<<(EE + 255) / 256, 256, 0, stream>>>(dst, iflags, cnt);
  k_scan<<<1, 1024, 0, stream>>>(cnt, offs, cursor);
  k_fill<<<(EE + 255) / 256, 256, 0, stream>>>(src, dst, iflags, cursor, esrc);
  k_soft<<<(NN * 8 + 255) / 256, 256, 0, stream>>>(el, er, offs, esrc, marr, darr);
  k_agg_s<<<(NN * 128 + 255) / 256, 256, 0, stream>>>(canon, z, el, er, marr, darr, offs, esrc, out);
  k_ffnrow<<<NN, 256, 0, stream>>>(canon, out);
}

// Round 12
// 438.236 us; speedup vs baseline: 3.4816x; 3.4816x over previous
//
#include <hip/hip_runtime.h>

#define NN 50000
#define EE 800000
#define LDK 136
#define LDI 264

// canonical bf16 region: element offsets
#define C_X    0
#define C_ZW   6400000   // zwt[c*128+d] = fc_w[c>>4][d][c&15]
#define C_AL   6416384
#define C_AR   6416512
#define C_LNG  6416640
#define C_LNB  6416768
#define C_W1T  6416896   // w1t[n*128+k] = w1[k*512+n]
#define C_B1   6482432
#define C_W2T  6482944   // w2t[n*512+k] = w2[k*128+n]
#define C_B2   6548480
#define C_TOT  6548608

typedef __attribute__((ext_vector_type(8))) short bf16x8;
typedef __attribute__((ext_vector_type(4))) float f32x4;

__device__ __forceinline__ float bf2f(unsigned short u) {
  union { unsigned int i; float f; } v; v.i = ((unsigned int)u) << 16; return v.f;
}
__device__ __forceinline__ unsigned short f2bf(float f) {
  union { float f; unsigned int i; } v; v.f = f;
  unsigned int r = v.i + 0x7fffu + ((v.i >> 16) & 1u);
  return (unsigned short)(r >> 16);
}
__device__ __forceinline__ int ld_idx(const void* p, int i, int is64) {
  return is64 ? (int)((const long long*)p)[i] : ((const int*)p)[i];
}

// ---- float dtype probe on x ----
__global__ void k_detect(const unsigned short* __restrict__ xr, int* __restrict__ flag) {
  int i = blockIdx.x * 256 + threadIdx.x;
  int bad = 0, zc = 0;
  for (int j = i; j < 65536; j += 32 * 256) {
    unsigned short u = xr[j];
    if ((u & 0x7F80u) == 0x7F80u) bad = 1;
    if (((j & 1) == 0) && u == 0) zc++;
  }
  if (bad) atomicOr(&flag[0], 1);
  if (zc) atomicAdd(&flag[1], zc);
}

// ---- int width probe ----
__global__ void k_detect_int(const int* __restrict__ s, const int* __restrict__ d,
                             int* __restrict__ iflags) {
  int i = blockIdx.x * 256 + threadIdx.x;
  int zs = 0, zd = 0;
  for (int j = i; j < 131072; j += 32 * 256) {
    if (j & 1) {
      if (s[j] == 0) zs++;
      if (d[j] == 0) zd++;
    }
  }
  if (zs) atomicAdd(&iflags[0], zs);
  if (zd) atomicAdd(&iflags[1], zd);
}

// ---- canonicalize float inputs -> bf16 canon (+ transposes) ----
__global__ __launch_bounds__(256) void k_convert(
    const void* __restrict__ x, const void* __restrict__ fcw,
    const void* __restrict__ a_l, const void* __restrict__ a_r,
    const void* __restrict__ lng, const void* __restrict__ lnb,
    const void* __restrict__ w1, const void* __restrict__ b1,
    const void* __restrict__ w2, const void* __restrict__ b2,
    const int* __restrict__ flag, unsigned short* __restrict__ canon) {
  const int isf32 = (flag[0] != 0) || (flag[1] > 8192);
  for (int i = blockIdx.x * 256 + threadIdx.x; i < C_TOT; i += gridDim.x * 256) {
    const void* src; int idx;
    if (i < C_ZW)       { src = x;   idx = i; }
    else if (i < C_AL)  { int j = i - C_ZW; int c = j >> 7, d = j & 127; src = fcw; idx = (c >> 4) * 2048 + d * 16 + (c & 15); }
    else if (i < C_AR)  { src = a_l; idx = i - C_AL; }
    else if (i < C_LNG) { src = a_r; idx = i - C_AR; }
    else if (i < C_LNB) { src = lng; idx = i - C_LNG; }
    else if (i < C_W1T) { src = lnb; idx = i - C_LNB; }
    else if (i < C_B1)  { int j = i - C_W1T; int n = j >> 7, k = j & 127; src = w1; idx = k * 512 + n; }
    else if (i < C_W2T) { src = b1;  idx = i - C_B1; }
    else if (i < C_B2)  { int j = i - C_W2T; int n = j >> 9, k = j & 511; src = w2; idx = k * 128 + n; }
    else                { src = b2;  idx = i - C_B2; }
    unsigned short v;
    if (isf32) v = f2bf(((const float*)src)[idx]);
    else       v = ((const unsigned short*)src)[idx];
    canon[i] = v;
  }
}

// ---- projection z = x@W (MFMA) with fused el/er ----
__global__ __launch_bounds__(256) void k_project(
    const unsigned short* __restrict__ canon,
    unsigned short* __restrict__ z, float* __restrict__ el, float* __restrict__ er) {
  const unsigned short* xc  = canon + C_X;
  const unsigned short* zwt = canon + C_ZW;
  const unsigned short* alc = canon + C_AL;
  const unsigned short* arc = canon + C_AR;
  __shared__ unsigned short sA[128 * LDK];
  __shared__ unsigned short sB[64 * LDK];
  const int tid = threadIdx.x;
  const int row0 = (blockIdx.x >> 1) * 128;
  const int n0 = (blockIdx.x & 1) * 64;
  for (int v = tid; v < 2048; v += 256) {
    int r = v >> 4, k8 = (v & 15) << 3;
    int gr = row0 + r; if (gr >= NN) gr = NN - 1;
    *(uint4*)(&sA[r * LDK + k8]) = *(const uint4*)(xc + gr * 128 + k8);
  }
  for (int v = tid; v < 1024; v += 256) {
    int n = v >> 4, k8 = (v & 15) << 3;
    *(uint4*)(&sB[n * LDK + k8]) = *(const uint4*)(zwt + (n0 + n) * 128 + k8);
  }
  __syncthreads();
  const int lane = tid & 63, w = tid >> 6;
  const int mr = lane & 15, q = lane >> 4;
  const f32x4 zero = {0.f, 0.f, 0.f, 0.f};
  f32x4 acc[8];
#pragma unroll
  for (int i = 0; i < 8; i++) acc[i] = zero;
#pragma unroll
  for (int kc = 0; kc < 4; kc++) {
    bf16x8 b = *(const bf16x8*)(&sB[(w * 16 + mr) * LDK + kc * 32 + q * 8]);
#pragma unroll
    for (int mt = 0; mt < 8; mt++) {
      bf16x8 a = *(const bf16x8*)(&sA[(mt * 16 + mr) * LDK + kc * 32 + q * 8]);
      acc[mt] = __builtin_amdgcn_mfma_f32_16x16x32_bf16(a, b, acc[mt], 0, 0, 0);
    }
  }
  const int col = n0 + w * 16 + mr;
  const int h = col >> 4;
  const float al = bf2f(alc[col]);
  const float ar = bf2f(arc[col]);
#pragma unroll
  for (int mt = 0; mt < 8; mt++) {
#pragma unroll
    for (int r = 0; r < 4; r++) {
      int grow = row0 + mt * 16 + q * 4 + r;
      float zv = acc[mt][r];
      float pl = zv * al, pr = zv * ar;
#pragma unroll
      for (int off = 1; off < 16; off <<= 1) {
        pl += __shfl_xor(pl, off);
        pr += __shfl_xor(pr, off);
      }
      if (grow < NN) {
        z[grow * 128 + col] = f2bf(zv);
        if (mr == 0) { el[grow * 8 + h] = pl; er[grow * 8 + h] = pr; }
      }
    }
  }
}

// ---------------- CSR build ----------------
__global__ void k_hist(const void* __restrict__ dst, const int* __restrict__ iflags,
                       int* __restrict__ cnt) {
  int i = blockIdx.x * 256 + threadIdx.x;
  if (i < EE) {
    int d64 = iflags[1] > 1000;
    unsigned d = (unsigned)ld_idx(dst, i, d64); if (d >= NN) d = 0;
    atomicAdd(&cnt[d], 1);
  }
}

__global__ __launch_bounds__(1024) void k_scan(const int* __restrict__ cnt,
                                               int* __restrict__ offs, int* __restrict__ cursor) {
  __shared__ int wtot[16];
  const int tid = threadIdx.x;
  const int lane = tid & 63, wid = tid >> 6;
  int carry = 0;
  for (int base = 0; base < NN; base += 4096) {
    int i0 = base + tid * 4;
    int c0 = 0, c1 = 0, c2 = 0, c3 = 0;
    if (i0 + 3 < NN) { int4 v = *(const int4*)(cnt + i0); c0 = v.x; c1 = v.y; c2 = v.z; c3 = v.w; }
    else {
      if (i0 < NN) c0 = cnt[i0];
      if (i0 + 1 < NN) c1 = cnt[i0 + 1];
      if (i0 + 2 < NN) c2 = cnt[i0 + 2];
      if (i0 + 3 < NN) c3 = cnt[i0 + 3];
    }
    int s = c0 + c1 + c2 + c3;
    int incl = s;
#pragma unroll
    for (int off = 1; off < 64; off <<= 1) {
      int t = __shfl_up(incl, off);
      if (lane >= off) incl += t;
    }
    if (lane == 63) wtot[wid] = incl;
    __syncthreads();
    int wbase = 0, total = 0;
    for (int j = 0; j < 16; j++) { int t = wtot[j]; total += t; if (j < wid) wbase += t; }
    int excl = carry + wbase + incl - s;
    if (i0 < NN) { offs[i0] = excl; cursor[i0] = excl; }
    if (i0 + 1 < NN) { offs[i0 + 1] = excl + c0; cursor[i0 + 1] = excl + c0; }
    if (i0 + 2 < NN) { offs[i0 + 2] = excl + c0 + c1; cursor[i0 + 2] = excl + c0 + c1; }
    if (i0 + 3 < NN) { offs[i0 + 3] = excl + c0 + c1 + c2; cursor[i0 + 3] = excl + c0 + c1 + c2; }
    carry += total;
    __syncthreads();
  }
  if (tid == 0) offs[NN] = carry;
}

__global__ void k_fill(const void* __restrict__ src, const void* __restrict__ dst,
                       const int* __restrict__ iflags,
                       int* __restrict__ cursor, int* __restrict__ esrc) {
  int i = blockIdx.x * 256 + threadIdx.x;
  if (i < EE) {
    int s64 = iflags[0] > 1000, d64 = iflags[1] > 1000;
    unsigned d = (unsigned)ld_idx(dst, i, d64); if (d >= NN) d = 0;
    int p = atomicAdd(&cursor[d], 1);
    unsigned s = (unsigned)ld_idx(src, i, s64); if (s >= NN) s = 0;
    if ((unsigned)p < EE) esrc[p] = (int)s;
  }
}

// ---- wave-per-node: softmax + aggregate + elu + residual -> h1 fp32 (d_out) ----
__global__ __launch_bounds__(256) void k_agg(
    const unsigned short* __restrict__ canon, const unsigned short* __restrict__ z,
    const float* __restrict__ el, const float* __restrict__ er,
    const int* __restrict__ offs, const int* __restrict__ esrc,
    float* __restrict__ h1out) {
  const unsigned short* xc = canon + C_X;
  const int lane = threadIdx.x & 63;
  const int node = blockIdx.x * 4 + (threadIdx.x >> 6);
  if (node >= NN) return;
  const int beg = offs[node];
  int deg = offs[node + 1] - beg;
  if (deg < 0 || deg > EE) deg = 0;
  const int hl = lane & 7;
  const float ern = er[node * 8 + hl];
  float m = -3.0e38f;
  for (int b = 0; b < deg; b += 8) {
    int ei = b + (lane >> 3);
    float ev = -3.0e38f;
    if (ei < deg) {
      unsigned s = (unsigned)esrc[beg + ei]; if (s >= NN) s = 0;
      float t = el[s * 8 + hl] + ern;
      ev = (t > 0.f) ? t : 0.01f * t;
    }
    m = fmaxf(m, ev);
  }
  m = fmaxf(m, __shfl_xor(m, 8));
  m = fmaxf(m, __shfl_xor(m, 16));
  m = fmaxf(m, __shfl_xor(m, 32));
  const int hc = lane >> 3;
  float denom = 0.f, a0 = 0.f, a1 = 0.f;
  for (int i = 0; i < deg; i++) {
    unsigned s = (unsigned)esrc[beg + i]; if (s >= NN) s = 0;
    float t = el[s * 8 + hl] + ern;
    t = (t > 0.f) ? t : 0.01f * t;
    float ex = __expf(fminf(t - m, 0.f));
    denom += ex;
    float exb = __shfl(ex, hc);
    unsigned int zz = *(const unsigned int*)(z + s * 128 + lane * 2);
    a0 += exb * bf2f((unsigned short)(zz & 0xffffu));
    a1 += exb * bf2f((unsigned short)(zz >> 16));
  }
  float dn = __shfl(denom, hc);
  float r0 = 0.f, r1 = 0.f;
  if (dn > 0.f) { float inv = 1.f / dn; r0 = a0 * inv; r1 = a1 * inv; }
  unsigned int xx = *(const unsigned int*)(xc + node * 128 + lane * 2);
  float hv0 = ((r0 > 0.f) ? r0 : (__expf(fminf(r0, 0.f)) - 1.f)) + bf2f((unsigned short)(xx & 0xffffu));
  float hv1 = ((r1 > 0.f) ? r1 : (__expf(fminf(r1, 0.f)) - 1.f)) + bf2f((unsigned short)(xx >> 16));
  float2 hp = make_float2(hv0, hv1);
  *(float2*)(h1out + node * 128 + lane * 2) = hp;
}

// ---- fused FFN (MFMA): LN -> gelu(ln@w1+b1)@w2 + b2 + h1, all on fp32 h1 in d_out ----
__global__ __launch_bounds__(256) void k_ffn(
    const unsigned short* __restrict__ canon, float* __restrict__ out) {
  const unsigned short* lngc = canon + C_LNG;
  const unsigned short* lnbc = canon + C_LNB;
  const unsigned short* w1t  = canon + C_W1T;
  const unsigned short* b1c  = canon + C_B1;
  const unsigned short* w2t  = canon + C_W2T;
  const unsigned short* b2c  = canon + C_B2;
  __shared__ unsigned short sLn[64 * LDK];
  __shared__ unsigned short sInt[64 * LDI];
  __shared__ float red[64][4];
  __shared__ float smu[64], srstd[64];
  const int tid = threadIdx.x;
  const int row0 = blockIdx.x * 64;
  // ---- LN prologue: 4 threads per row ----
  {
    const int r = tid >> 2, q4 = tid & 3;
    const int grow = row0 + r;
    float hv[32];
    float ps = 0.f;
    const float* hrow = out + (size_t)grow * 128 + q4 * 32;
#pragma unroll
    for (int j = 0; j < 32; j++) {
      hv[j] = (grow < NN) ? hrow[j] : 0.f;
      ps += hv[j];
    }
    red[r][q4] = ps;
    __syncthreads();
    if (q4 == 0) smu[r] = (red[r][0] + red[r][1] + red[r][2] + red[r][3]) * (1.f / 128.f);
    __syncthreads();
    const float mu = smu[r];
    float pv = 0.f;
#pragma unroll
    for (int j = 0; j < 32; j++) { float d = hv[j] - mu; pv += d * d; }
    red[r][q4] = pv;
    __syncthreads();
    if (q4 == 0) srstd[r] = rsqrtf((red[r][0] + red[r][1] + red[r][2] + red[r][3]) * (1.f / 128.f) + 1e-6f);
    __syncthreads();
    const float rs = srstd[r];
#pragma unroll
    for (int j = 0; j < 32; j++) {
      int c = q4 * 32 + j;
      sLn[r * LDK + c] = f2bf((hv[j] - mu) * rs * bf2f(lngc[c]) + bf2f(lnbc[c]));
    }
  }
  __syncthreads();
  // ---- GEMMs ----
  const int lane = tid & 63, w = tid >> 6;
  const int mr = lane & 15, q = lane >> 4;
  const f32x4 zero = {0.f, 0.f, 0.f, 0.f};
  f32x4 acc2[4][2];
#pragma unroll
  for (int a = 0; a < 4; a++) { acc2[a][0] = zero; acc2[a][1] = zero; }
#pragma unroll
  for (int half = 0; half < 2; half++) {
    if (half) __syncthreads();
    // GEMM1: inter cols [half*256 + w*64, +64)
#pragma unroll
    for (int nt = 0; nt < 4; nt++) {
      const int colg = half * 256 + w * 64 + nt * 16 + mr;
      f32x4 a1[4];
#pragma unroll
      for (int a = 0; a < 4; a++) a1[a] = zero;
#pragma unroll
      for (int kc = 0; kc < 4; kc++) {
        bf16x8 b = *(const bf16x8*)(w1t + colg * 128 + kc * 32 + q * 8);
#pragma unroll
        for (int mt = 0; mt < 4; mt++) {
          bf16x8 a = *(const bf16x8*)(&sLn[(mt * 16 + mr) * LDK + kc * 32 + q * 8]);
          a1[mt] = __builtin_amdgcn_mfma_f32_16x16x32_bf16(a, b, a1[mt], 0, 0, 0);
        }
      }
      const float bias = bf2f(b1c[colg]);
      const int coll = w * 64 + nt * 16 + mr;
#pragma unroll
      for (int mt = 0; mt < 4; mt++)
#pragma unroll
        for (int r = 0; r < 4; r++) {
          float v = a1[mt][r] + bias;
          float g = 0.5f * v * (1.f + erff(v * 0.7071067811865475f));
          sInt[(mt * 16 + q * 4 + r) * LDI + coll] = f2bf(g);
        }
    }
    __syncthreads();
    // GEMM2: K-chunk [half*256, +256), out cols [w*32, +32)
#pragma unroll
    for (int ks = 0; ks < 8; ks++) {
#pragma unroll
      for (int nt = 0; nt < 2; nt++) {
        const int colg = w * 32 + nt * 16 + mr;
        bf16x8 b = *(const bf16x8*)(w2t + colg * 512 + half * 256 + ks * 32 + q * 8);
#pragma unroll
        for (int mt = 0; mt < 4; mt++) {
          bf16x8 a = *(const bf16x8*)(&sInt[(mt * 16 + mr) * LDI + ks * 32 + q * 8]);
          acc2[mt][nt] = __builtin_amdgcn_mfma_f32_16x16x32_bf16(a, b, acc2[mt][nt], 0, 0, 0);
        }
      }
    }
  }
#pragma unroll
  for (int nt = 0; nt < 2; nt++) {
    const int col = w * 32 + nt * 16 + mr;
    const float bias = bf2f(b2c[col]);
#pragma unroll
    for (int mt = 0; mt < 4; mt++)
#pragma unroll
      for (int r = 0; r < 4; r++) {
        int grow = row0 + mt * 16 + q * 4 + r;
        if (grow < NN) {
          size_t o = (size_t)grow * 128 + col;
          out[o] = acc2[mt][nt][r] + bias + out[o];
        }
      }
  }
}

extern "C" void kernel_launch(void* const* d_in, const int* in_sizes, int n_in,
                              void* d_out, int out_size, void* d_ws, size_t ws_size,
                              hipStream_t stream) {
  const void* x   = d_in[0];
  const void* fcw = d_in[1];
  const void* a_l = d_in[2];
  const void* a_r = d_in[3];
  const void* lng = d_in[4];
  const void* lnb = d_in[5];
  const void* w1  = d_in[6];
  const void* b1  = d_in[7];
  const void* w2  = d_in[8];
  const void* b2  = d_in[9];
  const void* src = d_in[10];
  const void* dst = d_in[11];
  float* out = (float*)d_out;  // fp32 output

  char* ws = (char*)d_ws;
  size_t off = 0;
  auto alloc = [&](size_t bytes) -> char* {
    char* p = ws + off; off += (bytes + 255) & ~(size_t)255; return p;
  };
  int* flags            = (int*)alloc(64);   // [0,1]=float probe, [2,3]=int widths
  int* fflags           = flags;
  int* iflags           = flags + 2;
  int* cnt              = (int*)alloc((size_t)NN * 4);
  int* offs             = (int*)alloc((size_t)(NN + 1) * 4);
  int* cursor           = (int*)alloc((size_t)NN * 4);
  int* esrc             = (int*)alloc((size_t)EE * 4);
  unsigned short* canon = (unsigned short*)alloc((size_t)C_TOT * 2);
  unsigned short* z     = (unsigned short*)alloc((size_t)NN * 128 * 2);
  float* el             = (float*)alloc((size_t)NN * 8 * 4);
  float* er             = (float*)alloc((size_t)NN * 8 * 4);
  // total ≈ 32.9 MB (< verified-safe 36.5 MB)

  hipMemsetAsync(ws, 0, 256 + (size_t)NN * 4, stream);  // flags + cnt
  k_detect<<<32, 256, 0, stream>>>((const unsigned short*)x, fflags);
  k_detect_int<<<32, 256, 0, stream>>>((const int*)src, (const int*)dst, iflags);
  k_convert<<<2048, 256, 0, stream>>>(x, fcw, a_l, a_r, lng, lnb, w1, b1, w2, b2, fflags, canon);
  k_project<<<391 * 2, 256, 0, stream>>>(canon, z, el, er);
  k_hist<<<(EE + 255) / 256, 256, 0, stream>>>(dst, iflags, cnt);
  k_scan<<<1, 1024, 0, stream>>>(cnt, offs, cursor);
  k_fill<<<(EE + 255) / 256, 256, 0, stream>>>(src, dst, iflags, cursor, esrc);
  k_agg<<<(NN + 3) / 4, 256, 0, stream>>>(canon, z, el, er, offs, esrc, out);
  k_ffn<<<(NN + 63) / 64, 256, 0, stream>>>(canon, out);
}